// Round 10
// baseline (170.402 us; speedup 1.0000x reference)
//
#include <hip/hip_runtime.h>
#include <hip/hip_bf16.h>
#include <hip/hip_fp16.h>
#include <stdint.h>

typedef _Float16 half8_t __attribute__((ext_vector_type(8)));
typedef float f32x4_t __attribute__((ext_vector_type(4)));

// ---------------------------------------------------------------------------
// GCN 2-layer, fp16-MFMA path, chunk-major intermediates:
//   g = (x@W)*dis[row]  stored as [chunk][N][32] fp16 (chunk = 32 cols)
//   out[i] = dis[i]*(sum_e g[src]+g[i]) + b; aggregation chunk-pinned to XCD.
// CSR via dst-bucket binning + per-bucket LDS counting sort.
// gemm1: BK=64 (8 K-iters) to halve barrier-drain stall count.
// aggv: 4-lane/uint4 groups (16B gathers) to halve per-edge cost.
// ---------------------------------------------------------------------------

__global__ __launch_bounds__(256) void detect_i64_kernel(const int* __restrict__ idx,
                                                         int* __restrict__ flag,
                                                         int* __restrict__ bcnt) {
    int t = threadIdx.x;
    if (t < 64) {
        int v = idx[2 * t + 1];
        unsigned long long b = __ballot(v == 0);
        if (t == 0) *flag = (b == 0xFFFFFFFFFFFFFFFFULL) ? 1 : 0;
    }
    bcnt[t] = 0;
}

__device__ __forceinline__ int load_idx(const int* __restrict__ idx, long long pos, int is64) {
    return is64 ? idx[2 * pos] : idx[pos];
}

#define EPB 4096   // edges per binning block

// Pass 1: per-block LDS histogram of dst buckets -> global bucket counts.
__global__ __launch_bounds__(256) void bin_count_kernel(
        const int* __restrict__ idx, const int* __restrict__ flag,
        int* __restrict__ bcnt, int E, int N) {
    __shared__ int hist[256];
    hist[threadIdx.x] = 0;
    __syncthreads();
    const int is64 = *flag;
    const int base = blockIdx.x * EPB;
    const int cnt = (E - base < EPB) ? E - base : EPB;
    for (int i = threadIdx.x; i < cnt; i += 256) {
        int d = load_idx(idx, (long long)E + base + i, is64);
        if ((unsigned)d < (unsigned)N) atomicAdd(&hist[d >> 8], 1);
    }
    __syncthreads();
    int h = hist[threadIdx.x];
    if (h) atomicAdd(&bcnt[threadIdx.x], h);
}

// Scan bucket counts (NB <= 256) -> bbase (exclusive, NB+1) + bcur copy.
__global__ __launch_bounds__(256) void scan_buckets_kernel(
        const int* __restrict__ bcnt, int* __restrict__ bbase,
        int* __restrict__ bcur, int NB) {
    __shared__ int buf[256];
    int t = threadIdx.x;
    int v = (t < NB) ? bcnt[t] : 0;
    buf[t] = v;
    __syncthreads();
    #pragma unroll
    for (int off = 1; off < 256; off <<= 1) {
        int u = (t >= off) ? buf[t - off] : 0;
        __syncthreads();
        buf[t] += u;
        __syncthreads();
    }
    int excl = buf[t] - v;
    if (t < NB) { bbase[t] = excl; bcur[t] = excl; }
    if (t == NB - 1) bbase[NB] = buf[t];
}

// Pass 2: re-histogram, reserve contiguous per-(block,bucket) chunks with one
// global atomic each, then scatter packed records (src | dstlocal<<16).
__global__ __launch_bounds__(256) void bin_scatter_kernel(
        const int* __restrict__ idx, const int* __restrict__ flag,
        int* __restrict__ bcur, unsigned* __restrict__ packed, int E, int N) {
    __shared__ int cur[256];
    cur[threadIdx.x] = 0;
    __syncthreads();
    const int is64 = *flag;
    const int base = blockIdx.x * EPB;
    const int cnt = (E - base < EPB) ? E - base : EPB;
    for (int i = threadIdx.x; i < cnt; i += 256) {
        int d = load_idx(idx, (long long)E + base + i, is64);
        if ((unsigned)d < (unsigned)N) atomicAdd(&cur[d >> 8], 1);
    }
    __syncthreads();
    int h = cur[threadIdx.x];
    int bs = h ? atomicAdd(&bcur[threadIdx.x], h) : 0;
    __syncthreads();
    cur[threadIdx.x] = bs;
    __syncthreads();
    for (int i = threadIdx.x; i < cnt; i += 256) {
        int d = load_idx(idx, (long long)E + base + i, is64);
        if ((unsigned)d >= (unsigned)N) continue;
        int s = load_idx(idx, base + i, is64);
        if ((unsigned)s >= (unsigned)N) s = 0;
        int pos = atomicAdd(&cur[d >> 8], 1);
        packed[pos] = (unsigned)s | ((unsigned)(d & 255) << 16);
    }
}

// Per-bucket counting sort: packed records -> node-sorted csr_src + offsets + dis.
__global__ __launch_bounds__(256) void bucket_sort_kernel(
        const unsigned* __restrict__ packed, const int* __restrict__ bbase,
        int* __restrict__ csr_src, int* __restrict__ offsets,
        float* __restrict__ dis, int N, int NB) {
    __shared__ int buf[256];
    __shared__ int cur[256];
    const int b = blockIdx.x;
    const int t = threadIdx.x;
    cur[t] = 0;
    __syncthreads();
    const int e0 = bbase[b], e1 = bbase[b + 1];
    for (int i = e0 + t; i < e1; i += 256)
        atomicAdd(&cur[(packed[i] >> 16) & 255], 1);
    __syncthreads();
    int v = cur[t];
    buf[t] = v;
    __syncthreads();
    #pragma unroll
    for (int off = 1; off < 256; off <<= 1) {
        int u = (t >= off) ? buf[t - off] : 0;
        __syncthreads();
        buf[t] += u;
        __syncthreads();
    }
    int excl = buf[t] - v;
    cur[t] = excl;
    int node = b * 256 + t;
    if (node < N) {
        offsets[node] = e0 + excl;
        dis[node] = rsqrtf((float)(v + 1));   // +1 self-loop
    }
    if (b == NB - 1 && t == 0) offsets[N] = bbase[NB];
    __syncthreads();
    for (int i = e0 + t; i < e1; i += 256) {
        unsigned rec = packed[i];
        int dl = (rec >> 16) & 255;
        int pos = atomicAdd(&cur[dl], 1);
        csr_src[e0 + pos] = (int)(rec & 0xFFFF);
    }
}

// Transpose-convert W1 [512][256] -> w1t fp16 [256][512], W2 [256][64] -> w2t fp16 [64][256].
__global__ void wt_kernel(const float* __restrict__ W1, const float* __restrict__ W2,
                          _Float16* __restrict__ w1t, _Float16* __restrict__ w2t) {
    int p = blockIdx.x * 256 + threadIdx.x;
    if (p < 512 * 256) {
        int k = p >> 8, n = p & 255;
        w1t[n * 512 + k] = (_Float16)W1[p];
    } else {
        int q = p - 512 * 256;
        if (q < 256 * 64) {
            int k = q >> 6, n = q & 63;
            w2t[n * 256 + k] = (_Float16)W2[q];
        }
    }
}

// ---------------------------------------------------------------------------
// GEMM1: h1[chunk][M][32] = fp16( (x[M,512] @ W1) * dis[row] ).
// Tile 64 x 256, BK=64 (8 K-iters), 4 waves each 64x64, T14 reg-prefetch.
// LDS: As[8 kb][65 pad][8], Bs[8 kb][257 pad][8]; ~41 KB -> 3 blocks/CU.
// ---------------------------------------------------------------------------
__global__ __launch_bounds__(256, 3) void gemm1_kernel(
        const float* __restrict__ x, const _Float16* __restrict__ w1t,
        const float* __restrict__ dis, _Float16* __restrict__ h1s, int M) {
    __shared__ _Float16 As[8 * 65 * 8];
    __shared__ _Float16 Bs[8 * 257 * 8];
    const int tid = threadIdx.x;
    const int brow = blockIdx.x * 64;
    const int w = tid >> 6, lane = tid & 63;
    const int wcol = w * 64;
    const int lrow = lane & 15, lkb = lane >> 4;

    // A staging: thread -> (row = tid>>2, kq = tid&3 -> 16 consecutive floats).
    const int arow = tid >> 2, akq = tid & 3;
    const int gr = brow + arow;
    const bool aval = gr < M;
    const float* xptr = x + (size_t)(aval ? gr : 0) * 512 + akq * 16;
    // B staging: thread = col (0..255), 64 consecutive k = 128 B.
    const _Float16* bptr = w1t + (size_t)tid * 512;
    const int awr0 = ((akq * 2) * 65 + arow) << 3;
    const int awr1 = ((akq * 2 + 1) * 65 + arow) << 3;

    f32x4_t acc[4][4];
    #pragma unroll
    for (int mi = 0; mi < 4; ++mi)
        #pragma unroll
        for (int nj = 0; nj < 4; ++nj) acc[mi][nj] = (f32x4_t)0.f;

    float4 a0 = make_float4(0,0,0,0), a1 = a0, a2 = a0, a3 = a0;
    half8_t b[8];

    if (aval) {
        a0 = *(const float4*)(xptr);
        a1 = *(const float4*)(xptr + 4);
        a2 = *(const float4*)(xptr + 8);
        a3 = *(const float4*)(xptr + 12);
    }
    #pragma unroll
    for (int kb = 0; kb < 8; ++kb) b[kb] = *(const half8_t*)(bptr + kb * 8);

    for (int t = 0; t < 8; ++t) {
        __syncthreads();
        half8_t h0, h1;
        h0[0] = (_Float16)a0.x; h0[1] = (_Float16)a0.y;
        h0[2] = (_Float16)a0.z; h0[3] = (_Float16)a0.w;
        h0[4] = (_Float16)a1.x; h0[5] = (_Float16)a1.y;
        h0[6] = (_Float16)a1.z; h0[7] = (_Float16)a1.w;
        h1[0] = (_Float16)a2.x; h1[1] = (_Float16)a2.y;
        h1[2] = (_Float16)a2.z; h1[3] = (_Float16)a2.w;
        h1[4] = (_Float16)a3.x; h1[5] = (_Float16)a3.y;
        h1[6] = (_Float16)a3.z; h1[7] = (_Float16)a3.w;
        *(half8_t*)&As[awr0] = h0;
        *(half8_t*)&As[awr1] = h1;
        #pragma unroll
        for (int kb = 0; kb < 8; ++kb)
            *(half8_t*)&Bs[(kb * 257 + tid) << 3] = b[kb];
        __syncthreads();
        if (t < 7) {
            int k0 = (t + 1) * 64;
            if (aval) {
                a0 = *(const float4*)(xptr + k0);
                a1 = *(const float4*)(xptr + k0 + 4);
                a2 = *(const float4*)(xptr + k0 + 8);
                a3 = *(const float4*)(xptr + k0 + 12);
            }
            #pragma unroll
            for (int kb = 0; kb < 8; ++kb)
                b[kb] = *(const half8_t*)(bptr + k0 + kb * 8);
        }
        #pragma unroll
        for (int h = 0; h < 2; ++h) {
            half8_t af[4], bf[4];
            #pragma unroll
            for (int mi = 0; mi < 4; ++mi)
                af[mi] = *(const half8_t*)&As[((h * 4 + lkb) * 65 + mi * 16 + lrow) << 3];
            #pragma unroll
            for (int nj = 0; nj < 4; ++nj)
                bf[nj] = *(const half8_t*)&Bs[((h * 4 + lkb) * 257 + wcol + nj * 16 + lrow) << 3];
            #pragma unroll
            for (int mi = 0; mi < 4; ++mi)
                #pragma unroll
                for (int nj = 0; nj < 4; ++nj)
                    acc[mi][nj] = __builtin_amdgcn_mfma_f32_16x16x32_f16(af[mi], bf[nj], acc[mi][nj], 0, 0, 0);
        }
    }
    // Epilogue: C/D layout col=lane&15, row=(lane>>4)*4+r. Chunk-major store.
    #pragma unroll
    for (int mi = 0; mi < 4; ++mi) {
        #pragma unroll
        for (int r = 0; r < 4; ++r) {
            int grow = brow + mi * 16 + (lane >> 4) * 4 + r;
            if (grow >= M) continue;
            float s = dis[grow];
            #pragma unroll
            for (int nj = 0; nj < 4; ++nj) {
                int col = wcol + nj * 16 + lrow;
                h1s[((size_t)(col >> 5) * M + grow) * 32 + (col & 31)] =
                    (_Float16)(acc[mi][nj][r] * s);
            }
        }
    }
}

// ---------------------------------------------------------------------------
// GEMM2: h2[chunk][M][32] = fp16( (a1 @ W2) * dis[row] ), a1 chunk-major.
// Tile 64x64, 4 waves, K=256, T14 reg-prefetch.
// ---------------------------------------------------------------------------
__global__ __launch_bounds__(256, 4) void gemm2_kernel(
        const _Float16* __restrict__ a1s, const _Float16* __restrict__ w2t,
        const float* __restrict__ dis, _Float16* __restrict__ h2s, int M) {
    __shared__ _Float16 As[4 * 65 * 8];
    __shared__ _Float16 Bs[4 * 65 * 8];
    const int tid = threadIdx.x;
    const int brow = blockIdx.x * 64;
    const int w = tid >> 6, lane = tid & 63;
    const int lrow = lane & 15, lkb = lane >> 4;

    const int arow = tid >> 2, akb = tid & 3;
    const int gr = brow + arow;
    const bool aval = gr < M;
    const _Float16* aptr = a1s + ((size_t)(aval ? gr : 0)) * 32 + akb * 8;
    const _Float16* bptr = w2t + (size_t)arow * 256 + akb * 8;
    const int awr = (akb * 65 + arow) << 3;

    f32x4_t acc[4];
    #pragma unroll
    for (int nj = 0; nj < 4; ++nj) acc[nj] = (f32x4_t)0.f;

    const half8_t zero8 = (half8_t)(_Float16)0.f;
    half8_t ah = zero8, bh;
    if (aval) ah = *(const half8_t*)(aptr);
    bh = *(const half8_t*)(bptr);

    for (int t = 0; t < 8; ++t) {
        __syncthreads();
        *(half8_t*)&As[awr] = ah;
        *(half8_t*)&Bs[awr] = bh;
        __syncthreads();
        if (t < 7) {
            if (aval) ah = *(const half8_t*)(aptr + (size_t)(t + 1) * M * 32);
            bh = *(const half8_t*)(bptr + (t + 1) * 32);
        }
        half8_t a = *(const half8_t*)&As[(lkb * 65 + w * 16 + lrow) << 3];
        half8_t b[4];
        #pragma unroll
        for (int nj = 0; nj < 4; ++nj)
            b[nj] = *(const half8_t*)&Bs[(lkb * 65 + nj * 16 + lrow) << 3];
        #pragma unroll
        for (int nj = 0; nj < 4; ++nj)
            acc[nj] = __builtin_amdgcn_mfma_f32_16x16x32_f16(a, b[nj], acc[nj], 0, 0, 0);
    }
    #pragma unroll
    for (int r = 0; r < 4; ++r) {
        int grow = brow + w * 16 + (lane >> 4) * 4 + r;
        if (grow >= M) continue;
        float s = dis[grow];
        #pragma unroll
        for (int nj = 0; nj < 4; ++nj) {
            int col = nj * 16 + lrow;
            h2s[((size_t)(col >> 5) * M + grow) * 32 + (col & 31)] =
                (_Float16)(acc[nj][r] * s);
        }
    }
}

__device__ __forceinline__ float4 up4(uint2 v) {
    __half2 h0 = *reinterpret_cast<__half2*>(&v.x);
    __half2 h1 = *reinterpret_cast<__half2*>(&v.y);
    float2 a = __half22float2(h0), b = __half22float2(h1);
    return make_float4(a.x, a.y, b.x, b.y);
}

__device__ __forceinline__ unsigned pkw(unsigned a, unsigned b) {
    __half2 ha = *reinterpret_cast<__half2*>(&a);
    __half2 hb = *reinterpret_cast<__half2*>(&b);
    __half2 r = __hadd2(ha, hb);
    return *reinterpret_cast<unsigned*>(&r);
}

__device__ __forceinline__ uint4 pk4(uint4 a, uint4 b) {
    uint4 r;
    r.x = pkw(a.x, b.x);
    r.y = pkw(a.y, b.y);
    r.z = pkw(a.z, b.z);
    r.w = pkw(a.w, b.w);
    return r;
}

// ---------------------------------------------------------------------------
// Chunked aggregation over [NCH][N][32] fp16, chunk pinned via blockIdx % NCH.
// Block = 64 nodes; stages the block's contiguous CSR slice into LDS.
// 4-lane group per node (lane = uint4 = 8 fp16); depth-2 fp16 pairwise tree,
// f32 master accumulators (8 floats/lane).
// ---------------------------------------------------------------------------
template<int NCH, int FP16OUT>
__global__ __launch_bounds__(256) void aggv_kernel(
        const _Float16* __restrict__ g, const int* __restrict__ offsets,
        const int* __restrict__ csr_src, const float* __restrict__ dis,
        const float* __restrict__ bias, void* __restrict__ out, int N) {
    constexpr int CAP = 2048;
    __shared__ int lds_csr[CAP];
    const int chunk = blockIdx.x % NCH;
    const int nodeBase = (blockIdx.x / NCH) * 64;
    const int grp = threadIdx.x >> 2;     // 0..63
    const int cl = threadIdx.x & 3;       // uint4 slot (8 fp16)
    const int node = nodeBase + grp;
    const bool active = node < N;
    const int nend = (nodeBase + 64 < N) ? nodeBase + 64 : N;
    const int blk0 = offsets[nodeBase];
    const int blk1 = offsets[nend];
    const uint4* gc = (const uint4*)g + (size_t)chunk * N * 4;   // row = 4 uint4

    int gs0 = 0, gs1 = 0;
    float s = 0.f;
    if (active) { gs0 = offsets[node]; gs1 = offsets[node + 1]; s = dis[node]; }

    float4 accLo = make_float4(0.f, 0.f, 0.f, 0.f);
    float4 accHi = make_float4(0.f, 0.f, 0.f, 0.f);
    if (active) {
        uint4 sv = gc[(size_t)node * 4 + cl];                    // self-loop
        float4 lo = up4(make_uint2(sv.x, sv.y));
        float4 hi = up4(make_uint2(sv.z, sv.w));
        accLo.x += lo.x; accLo.y += lo.y; accLo.z += lo.z; accLo.w += lo.w;
        accHi.x += hi.x; accHi.y += hi.y; accHi.z += hi.z; accHi.w += hi.w;
    }

    for (int base = blk0; base < blk1; base += CAP) {
        const int cnt = (blk1 - base < CAP) ? blk1 - base : CAP;
        __syncthreads();
        for (int i = threadIdx.x; i < cnt; i += 256)
            lds_csr[i] = csr_src[base + i];
        __syncthreads();
        int lo_e = (gs0 > base ? gs0 : base) - base;
        int hi_e = (gs1 < base + cnt ? gs1 : base + cnt) - base;
        int e = lo_e;
        for (; e + 4 <= hi_e; e += 4) {
            int s0 = lds_csr[e], s1 = lds_csr[e + 1];
            int s2 = lds_csr[e + 2], s3 = lds_csr[e + 3];
            uint4 v0 = gc[(size_t)s0 * 4 + cl];
            uint4 v1 = gc[(size_t)s1 * 4 + cl];
            uint4 v2 = gc[(size_t)s2 * 4 + cl];
            uint4 v3 = gc[(size_t)s3 * 4 + cl];
            uint4 q = pk4(pk4(v0, v1), pk4(v2, v3));   // depth-2 fp16 tree
            float4 flo = up4(make_uint2(q.x, q.y));
            float4 fhi = up4(make_uint2(q.z, q.w));
            accLo.x += flo.x; accLo.y += flo.y; accLo.z += flo.z; accLo.w += flo.w;
            accHi.x += fhi.x; accHi.y += fhi.y; accHi.z += fhi.z; accHi.w += fhi.w;
        }
        for (; e < hi_e; ++e) {
            int s0 = lds_csr[e];
            uint4 v = gc[(size_t)s0 * 4 + cl];
            float4 flo = up4(make_uint2(v.x, v.y));
            float4 fhi = up4(make_uint2(v.z, v.w));
            accLo.x += flo.x; accLo.y += flo.y; accLo.z += flo.z; accLo.w += flo.w;
            accHi.x += fhi.x; accHi.y += fhi.y; accHi.z += fhi.z; accHi.w += fhi.w;
        }
    }
    if (active) {
        float4 bb0 = *(const float4*)&bias[chunk * 32 + cl * 8];
        float4 bb1 = *(const float4*)&bias[chunk * 32 + cl * 8 + 4];
        float4 o0, o1;
        o0.x = fmaf(s, accLo.x, bb0.x);
        o0.y = fmaf(s, accLo.y, bb0.y);
        o0.z = fmaf(s, accLo.z, bb0.z);
        o0.w = fmaf(s, accLo.w, bb0.w);
        o1.x = fmaf(s, accHi.x, bb1.x);
        o1.y = fmaf(s, accHi.y, bb1.y);
        o1.z = fmaf(s, accHi.z, bb1.z);
        o1.w = fmaf(s, accHi.w, bb1.w);
        if (FP16OUT) {
            o0.x = fmaxf(o0.x, 0.f); o0.y = fmaxf(o0.y, 0.f);
            o0.z = fmaxf(o0.z, 0.f); o0.w = fmaxf(o0.w, 0.f);
            o1.x = fmaxf(o1.x, 0.f); o1.y = fmaxf(o1.y, 0.f);
            o1.z = fmaxf(o1.z, 0.f); o1.w = fmaxf(o1.w, 0.f);
            __half2 p0 = __float22half2_rn(make_float2(o0.x, o0.y));
            __half2 p1 = __float22half2_rn(make_float2(o0.z, o0.w));
            __half2 p2 = __float22half2_rn(make_float2(o1.x, o1.y));
            __half2 p3 = __float22half2_rn(make_float2(o1.z, o1.w));
            uint4 pv;
            pv.x = *reinterpret_cast<unsigned*>(&p0);
            pv.y = *reinterpret_cast<unsigned*>(&p1);
            pv.z = *reinterpret_cast<unsigned*>(&p2);
            pv.w = *reinterpret_cast<unsigned*>(&p3);
            ((uint4*)out)[((size_t)chunk * N + node) * 4 + cl] = pv;
        } else {
            ((float4*)out)[(size_t)node * (NCH * 8) + chunk * 8 + cl * 2]     = o0;
            ((float4*)out)[(size_t)node * (NCH * 8) + chunk * 8 + cl * 2 + 1] = o1;
        }
    }
}

extern "C" void kernel_launch(void* const* d_in, const int* in_sizes, int n_in,
                              void* d_out, int out_size, void* d_ws, size_t ws_size,
                              hipStream_t stream) {
    const float* x  = (const float*)d_in[0];
    const float* W1 = (const float*)d_in[1];
    const float* b1 = (const float*)d_in[2];
    const float* W2 = (const float*)d_in[3];
    const float* b2 = (const float*)d_in[4];
    const int* eidx = (const int*)d_in[5];

    const int HID = in_sizes[2];            // 256
    const int OUT = in_sizes[4];            // 64
    const int IN  = in_sizes[1] / HID;      // 512
    const int N   = in_sizes[0] / IN;       // 50000
    const int E   = in_sizes[5] / 2;        // 800000
    const int NB  = (N + 255) >> 8;         // 196 buckets

    char* ws = (char*)d_ws;
    size_t off = 0;
    auto alloc = [&](size_t bytes) {
        off = (off + 255) & ~(size_t)255;
        char* p = ws + off;
        off += bytes;
        return p;
    };
    float* dis       = (float*)alloc((size_t)N * 4);
    int* flag        = (int*)alloc(256);
    int* bcnt        = (int*)alloc(256 * 4);
    int* bbase       = (int*)alloc(260 * 4);
    int* bcur        = (int*)alloc(256 * 4);
    int* offsets     = (int*)alloc((size_t)(N + 1) * 4);
    unsigned* packed = (unsigned*)alloc((size_t)E * 4);
    int* csr_src     = (int*)alloc((size_t)E * 4);
    _Float16* w1t    = (_Float16*)alloc((size_t)IN * HID * 2);
    _Float16* w2t    = (_Float16*)alloc((size_t)HID * OUT * 2);
    _Float16* h1s    = (_Float16*)alloc((size_t)N * HID * 2);   // [8][N][32]
    _Float16* a1s    = (_Float16*)alloc((size_t)N * HID * 2);   // [8][N][32]
    _Float16* h2s    = (_Float16*)alloc((size_t)N * OUT * 2);   // [2][N][32]

    const int nblkE = (E + EPB - 1) / EPB;

    detect_i64_kernel<<<1, 256, 0, stream>>>(eidx, flag, bcnt);
    bin_count_kernel<<<nblkE, 256, 0, stream>>>(eidx, flag, bcnt, E, N);
    scan_buckets_kernel<<<1, 256, 0, stream>>>(bcnt, bbase, bcur, NB);
    bin_scatter_kernel<<<nblkE, 256, 0, stream>>>(eidx, flag, bcur, packed, E, N);
    bucket_sort_kernel<<<NB, 256, 0, stream>>>(packed, bbase, csr_src, offsets, dis, N, NB);
    wt_kernel<<<(IN * HID + HID * OUT + 255) / 256, 256, 0, stream>>>(W1, W2, w1t, w2t);

    // Layer 1
    gemm1_kernel<<<(N + 63) / 64, 256, 0, stream>>>(x, w1t, dis, h1s, N);
    aggv_kernel<8, 1><<<((N + 63) / 64) * 8, 256, 0, stream>>>(h1s, offsets, csr_src, dis,
                                                               b1, a1s, N);
    // Layer 2
    gemm2_kernel<<<(N + 63) / 64, 256, 0, stream>>>(a1s, w2t, dis, h2s, N);
    aggv_kernel<2, 0><<<((N + 63) / 64) * 2, 256, 0, stream>>>(h2s, offsets, csr_src, dis,
                                                               b2, d_out, N);
}

// Round 11
// 158.107 us; speedup vs baseline: 1.0778x; 1.0778x over previous
//
#include <hip/hip_runtime.h>
#include <hip/hip_bf16.h>
#include <hip/hip_fp16.h>
#include <stdint.h>

typedef _Float16 half8_t __attribute__((ext_vector_type(8)));
typedef _Float16 half4_t __attribute__((ext_vector_type(4)));
typedef float f32x4_t __attribute__((ext_vector_type(4)));

// ---------------------------------------------------------------------------
// GCN 2-layer, fp16-MFMA path, chunk-major intermediates:
//   g = (x@W)*dis[row]  stored as [chunk][N][32] fp16 (chunk = 32 cols)
//   out[i] = dis[i]*(sum_e g[src]+g[i]) + b; aggregation chunk-pinned to XCD.
// CSR via dst-bucket binning + per-bucket LDS counting sort.
// gemm1: BM=32 x BN=256, BK=32 -> 1563 blocks (6/CU) for latency-hiding TLP.
// aggv: 4-lane/uint4 groups, LDS-staged CSR, fp16 pairwise tree.
// ---------------------------------------------------------------------------

__global__ __launch_bounds__(256) void detect_i64_kernel(const int* __restrict__ idx,
                                                         int* __restrict__ flag,
                                                         int* __restrict__ bcnt) {
    int t = threadIdx.x;
    if (t < 64) {
        int v = idx[2 * t + 1];
        unsigned long long b = __ballot(v == 0);
        if (t == 0) *flag = (b == 0xFFFFFFFFFFFFFFFFULL) ? 1 : 0;
    }
    bcnt[t] = 0;
}

__device__ __forceinline__ int load_idx(const int* __restrict__ idx, long long pos, int is64) {
    return is64 ? idx[2 * pos] : idx[pos];
}

#define EPB 4096   // edges per binning block

__global__ __launch_bounds__(256) void bin_count_kernel(
        const int* __restrict__ idx, const int* __restrict__ flag,
        int* __restrict__ bcnt, int E, int N) {
    __shared__ int hist[256];
    hist[threadIdx.x] = 0;
    __syncthreads();
    const int is64 = *flag;
    const int base = blockIdx.x * EPB;
    const int cnt = (E - base < EPB) ? E - base : EPB;
    for (int i = threadIdx.x; i < cnt; i += 256) {
        int d = load_idx(idx, (long long)E + base + i, is64);
        if ((unsigned)d < (unsigned)N) atomicAdd(&hist[d >> 8], 1);
    }
    __syncthreads();
    int h = hist[threadIdx.x];
    if (h) atomicAdd(&bcnt[threadIdx.x], h);
}

__global__ __launch_bounds__(256) void scan_buckets_kernel(
        const int* __restrict__ bcnt, int* __restrict__ bbase,
        int* __restrict__ bcur, int NB) {
    __shared__ int buf[256];
    int t = threadIdx.x;
    int v = (t < NB) ? bcnt[t] : 0;
    buf[t] = v;
    __syncthreads();
    #pragma unroll
    for (int off = 1; off < 256; off <<= 1) {
        int u = (t >= off) ? buf[t - off] : 0;
        __syncthreads();
        buf[t] += u;
        __syncthreads();
    }
    int excl = buf[t] - v;
    if (t < NB) { bbase[t] = excl; bcur[t] = excl; }
    if (t == NB - 1) bbase[NB] = buf[t];
}

__global__ __launch_bounds__(256) void bin_scatter_kernel(
        const int* __restrict__ idx, const int* __restrict__ flag,
        int* __restrict__ bcur, unsigned* __restrict__ packed, int E, int N) {
    __shared__ int cur[256];
    cur[threadIdx.x] = 0;
    __syncthreads();
    const int is64 = *flag;
    const int base = blockIdx.x * EPB;
    const int cnt = (E - base < EPB) ? E - base : EPB;
    for (int i = threadIdx.x; i < cnt; i += 256) {
        int d = load_idx(idx, (long long)E + base + i, is64);
        if ((unsigned)d < (unsigned)N) atomicAdd(&cur[d >> 8], 1);
    }
    __syncthreads();
    int h = cur[threadIdx.x];
    int bs = h ? atomicAdd(&bcur[threadIdx.x], h) : 0;
    __syncthreads();
    cur[threadIdx.x] = bs;
    __syncthreads();
    for (int i = threadIdx.x; i < cnt; i += 256) {
        int d = load_idx(idx, (long long)E + base + i, is64);
        if ((unsigned)d >= (unsigned)N) continue;
        int s = load_idx(idx, base + i, is64);
        if ((unsigned)s >= (unsigned)N) s = 0;
        int pos = atomicAdd(&cur[d >> 8], 1);
        packed[pos] = (unsigned)s | ((unsigned)(d & 255) << 16);
    }
}

__global__ __launch_bounds__(256) void bucket_sort_kernel(
        const unsigned* __restrict__ packed, const int* __restrict__ bbase,
        int* __restrict__ csr_src, int* __restrict__ offsets,
        float* __restrict__ dis, int N, int NB) {
    __shared__ int buf[256];
    __shared__ int cur[256];
    const int b = blockIdx.x;
    const int t = threadIdx.x;
    cur[t] = 0;
    __syncthreads();
    const int e0 = bbase[b], e1 = bbase[b + 1];
    for (int i = e0 + t; i < e1; i += 256)
        atomicAdd(&cur[(packed[i] >> 16) & 255], 1);
    __syncthreads();
    int v = cur[t];
    buf[t] = v;
    __syncthreads();
    #pragma unroll
    for (int off = 1; off < 256; off <<= 1) {
        int u = (t >= off) ? buf[t - off] : 0;
        __syncthreads();
        buf[t] += u;
        __syncthreads();
    }
    int excl = buf[t] - v;
    cur[t] = excl;
    int node = b * 256 + t;
    if (node < N) {
        offsets[node] = e0 + excl;
        dis[node] = rsqrtf((float)(v + 1));   // +1 self-loop
    }
    if (b == NB - 1 && t == 0) offsets[N] = bbase[NB];
    __syncthreads();
    for (int i = e0 + t; i < e1; i += 256) {
        unsigned rec = packed[i];
        int dl = (rec >> 16) & 255;
        int pos = atomicAdd(&cur[dl], 1);
        csr_src[e0 + pos] = (int)(rec & 0xFFFF);
    }
}

// Transpose-convert W1 [512][256] -> w1t fp16 [256][512], W2 [256][64] -> w2t fp16 [64][256].
__global__ void wt_kernel(const float* __restrict__ W1, const float* __restrict__ W2,
                          _Float16* __restrict__ w1t, _Float16* __restrict__ w2t) {
    int p = blockIdx.x * 256 + threadIdx.x;
    if (p < 512 * 256) {
        int k = p >> 8, n = p & 255;
        w1t[n * 512 + k] = (_Float16)W1[p];
    } else {
        int q = p - 512 * 256;
        if (q < 256 * 64) {
            int k = q >> 6, n = q & 63;
            w2t[n * 256 + k] = (_Float16)W2[q];
        }
    }
}

// ---------------------------------------------------------------------------
// GEMM1: h1[chunk][M][32] = fp16( (x[M,512] @ W1) * dis[row] ).
// Tile 32 x 256, BK=32, 4 waves each 32x64, 1563 blocks. T14 reg-prefetch.
// LDS: As[4 kb][33 pad][8], Bs[4 kb][257 pad][8] ~ 18.6 KB.
// ---------------------------------------------------------------------------
__global__ __launch_bounds__(256, 4) void gemm1_kernel(
        const float* __restrict__ x, const _Float16* __restrict__ w1t,
        const float* __restrict__ dis, _Float16* __restrict__ h1s, int M) {
    __shared__ _Float16 As[4 * 33 * 8];
    __shared__ _Float16 Bs[4 * 257 * 8];
    const int tid = threadIdx.x;
    const int brow = blockIdx.x * 32;
    const int w = tid >> 6, lane = tid & 63;
    const int wcol = w * 64;
    const int lrow = lane & 15, lkb = lane >> 4;

    // A staging: thread -> (row = tid>>3, kb = (tid>>1)&3, half = tid&1), float4.
    const int arow = tid >> 3, akb = (tid >> 1) & 3, ahalf = tid & 1;
    const int gr = brow + arow;
    const bool aval = gr < M;
    const float* xptr = x + (size_t)(aval ? gr : 0) * 512 + akb * 8 + ahalf * 4;
    // B staging: 4 pieces p = tid + i*256 -> (col = p>>2, kb = p&3), half8.
    const _Float16* bbase = w1t + (size_t)(tid >> 2) * 512 + (tid & 3) * 8;
    const int awr = ((akb * 33 + arow) << 3) + ahalf * 4;
    const int bwr0 = (((tid & 3) * 257 + (tid >> 2)) << 3);

    f32x4_t acc[2][4];
    #pragma unroll
    for (int mi = 0; mi < 2; ++mi)
        #pragma unroll
        for (int nj = 0; nj < 4; ++nj) acc[mi][nj] = (f32x4_t)0.f;

    float4 av = make_float4(0.f, 0.f, 0.f, 0.f);
    half8_t bh0, bh1, bh2, bh3;

    // Prefetch tile 0.
    if (aval) av = *(const float4*)(xptr);
    bh0 = *(const half8_t*)(bbase);
    bh1 = *(const half8_t*)(bbase + 64 * 512);
    bh2 = *(const half8_t*)(bbase + 128 * 512);
    bh3 = *(const half8_t*)(bbase + 192 * 512);

    for (int t = 0; t < 16; ++t) {
        __syncthreads();
        half4_t ha;
        ha[0] = (_Float16)av.x; ha[1] = (_Float16)av.y;
        ha[2] = (_Float16)av.z; ha[3] = (_Float16)av.w;
        *(half4_t*)&As[awr] = ha;
        *(half8_t*)&Bs[bwr0] = bh0;
        *(half8_t*)&Bs[bwr0 + 64 * 8] = bh1;
        *(half8_t*)&Bs[bwr0 + 128 * 8] = bh2;
        *(half8_t*)&Bs[bwr0 + 192 * 8] = bh3;
        __syncthreads();
        if (t < 15) {
            int k0 = (t + 1) * 32;
            if (aval) av = *(const float4*)(xptr + k0);
            bh0 = *(const half8_t*)(bbase + k0);
            bh1 = *(const half8_t*)(bbase + k0 + 64 * 512);
            bh2 = *(const half8_t*)(bbase + k0 + 128 * 512);
            bh3 = *(const half8_t*)(bbase + k0 + 192 * 512);
        }
        half8_t af[2], bf[4];
        #pragma unroll
        for (int mi = 0; mi < 2; ++mi)
            af[mi] = *(const half8_t*)&As[(lkb * 33 + mi * 16 + lrow) << 3];
        #pragma unroll
        for (int nj = 0; nj < 4; ++nj)
            bf[nj] = *(const half8_t*)&Bs[(lkb * 257 + wcol + nj * 16 + lrow) << 3];
        #pragma unroll
        for (int mi = 0; mi < 2; ++mi)
            #pragma unroll
            for (int nj = 0; nj < 4; ++nj)
                acc[mi][nj] = __builtin_amdgcn_mfma_f32_16x16x32_f16(af[mi], bf[nj], acc[mi][nj], 0, 0, 0);
    }
    // Epilogue: C/D layout col=lane&15, row=(lane>>4)*4+r. Chunk-major store.
    #pragma unroll
    for (int mi = 0; mi < 2; ++mi) {
        #pragma unroll
        for (int r = 0; r < 4; ++r) {
            int grow = brow + mi * 16 + (lane >> 4) * 4 + r;
            if (grow >= M) continue;
            float s = dis[grow];
            #pragma unroll
            for (int nj = 0; nj < 4; ++nj) {
                int col = wcol + nj * 16 + lrow;
                h1s[((size_t)(col >> 5) * M + grow) * 32 + (col & 31)] =
                    (_Float16)(acc[mi][nj][r] * s);
            }
        }
    }
}

// ---------------------------------------------------------------------------
// GEMM2: h2[chunk][M][32] = fp16( (a1 @ W2) * dis[row] ), a1 chunk-major.
// Tile 64x64, 4 waves, K=256, T14 reg-prefetch.
// ---------------------------------------------------------------------------
__global__ __launch_bounds__(256, 4) void gemm2_kernel(
        const _Float16* __restrict__ a1s, const _Float16* __restrict__ w2t,
        const float* __restrict__ dis, _Float16* __restrict__ h2s, int M) {
    __shared__ _Float16 As[4 * 65 * 8];
    __shared__ _Float16 Bs[4 * 65 * 8];
    const int tid = threadIdx.x;
    const int brow = blockIdx.x * 64;
    const int w = tid >> 6, lane = tid & 63;
    const int lrow = lane & 15, lkb = lane >> 4;

    const int arow = tid >> 2, akb = tid & 3;
    const int gr = brow + arow;
    const bool aval = gr < M;
    const _Float16* aptr = a1s + ((size_t)(aval ? gr : 0)) * 32 + akb * 8;
    const _Float16* bptr = w2t + (size_t)arow * 256 + akb * 8;
    const int awr = (akb * 65 + arow) << 3;

    f32x4_t acc[4];
    #pragma unroll
    for (int nj = 0; nj < 4; ++nj) acc[nj] = (f32x4_t)0.f;

    const half8_t zero8 = (half8_t)(_Float16)0.f;
    half8_t ah = zero8, bh;
    if (aval) ah = *(const half8_t*)(aptr);
    bh = *(const half8_t*)(bptr);

    for (int t = 0; t < 8; ++t) {
        __syncthreads();
        *(half8_t*)&As[awr] = ah;
        *(half8_t*)&Bs[awr] = bh;
        __syncthreads();
        if (t < 7) {
            if (aval) ah = *(const half8_t*)(aptr + (size_t)(t + 1) * M * 32);
            bh = *(const half8_t*)(bptr + (t + 1) * 32);
        }
        half8_t a = *(const half8_t*)&As[(lkb * 65 + w * 16 + lrow) << 3];
        half8_t b[4];
        #pragma unroll
        for (int nj = 0; nj < 4; ++nj)
            b[nj] = *(const half8_t*)&Bs[(lkb * 65 + nj * 16 + lrow) << 3];
        #pragma unroll
        for (int nj = 0; nj < 4; ++nj)
            acc[nj] = __builtin_amdgcn_mfma_f32_16x16x32_f16(a, b[nj], acc[nj], 0, 0, 0);
    }
    #pragma unroll
    for (int r = 0; r < 4; ++r) {
        int grow = brow + w * 16 + (lane >> 4) * 4 + r;
        if (grow >= M) continue;
        float s = dis[grow];
        #pragma unroll
        for (int nj = 0; nj < 4; ++nj) {
            int col = nj * 16 + lrow;
            h2s[((size_t)(col >> 5) * M + grow) * 32 + (col & 31)] =
                (_Float16)(acc[nj][r] * s);
        }
    }
}

__device__ __forceinline__ float4 up4(uint2 v) {
    __half2 h0 = *reinterpret_cast<__half2*>(&v.x);
    __half2 h1 = *reinterpret_cast<__half2*>(&v.y);
    float2 a = __half22float2(h0), b = __half22float2(h1);
    return make_float4(a.x, a.y, b.x, b.y);
}

__device__ __forceinline__ unsigned pkw(unsigned a, unsigned b) {
    __half2 ha = *reinterpret_cast<__half2*>(&a);
    __half2 hb = *reinterpret_cast<__half2*>(&b);
    __half2 r = __hadd2(ha, hb);
    return *reinterpret_cast<unsigned*>(&r);
}

__device__ __forceinline__ uint4 pk4(uint4 a, uint4 b) {
    uint4 r;
    r.x = pkw(a.x, b.x);
    r.y = pkw(a.y, b.y);
    r.z = pkw(a.z, b.z);
    r.w = pkw(a.w, b.w);
    return r;
}

// ---------------------------------------------------------------------------
// Chunked aggregation over [NCH][N][32] fp16, chunk pinned via blockIdx % NCH.
// Block = 64 nodes; stages the block's contiguous CSR slice into LDS.
// 4-lane group per node (lane = uint4 = 8 fp16); depth-2 fp16 pairwise tree,
// f32 master accumulators (8 floats/lane).
// ---------------------------------------------------------------------------
template<int NCH, int FP16OUT>
__global__ __launch_bounds__(256) void aggv_kernel(
        const _Float16* __restrict__ g, const int* __restrict__ offsets,
        const int* __restrict__ csr_src, const float* __restrict__ dis,
        const float* __restrict__ bias, void* __restrict__ out, int N) {
    constexpr int CAP = 2048;
    __shared__ int lds_csr[CAP];
    const int chunk = blockIdx.x % NCH;
    const int nodeBase = (blockIdx.x / NCH) * 64;
    const int grp = threadIdx.x >> 2;     // 0..63
    const int cl = threadIdx.x & 3;       // uint4 slot (8 fp16)
    const int node = nodeBase + grp;
    const bool active = node < N;
    const int nend = (nodeBase + 64 < N) ? nodeBase + 64 : N;
    const int blk0 = offsets[nodeBase];
    const int blk1 = offsets[nend];
    const uint4* gc = (const uint4*)g + (size_t)chunk * N * 4;   // row = 4 uint4

    int gs0 = 0, gs1 = 0;
    float s = 0.f;
    if (active) { gs0 = offsets[node]; gs1 = offsets[node + 1]; s = dis[node]; }

    float4 accLo = make_float4(0.f, 0.f, 0.f, 0.f);
    float4 accHi = make_float4(0.f, 0.f, 0.f, 0.f);
    if (active) {
        uint4 sv = gc[(size_t)node * 4 + cl];                    // self-loop
        float4 lo = up4(make_uint2(sv.x, sv.y));
        float4 hi = up4(make_uint2(sv.z, sv.w));
        accLo.x += lo.x; accLo.y += lo.y; accLo.z += lo.z; accLo.w += lo.w;
        accHi.x += hi.x; accHi.y += hi.y; accHi.z += hi.z; accHi.w += hi.w;
    }

    for (int base = blk0; base < blk1; base += CAP) {
        const int cnt = (blk1 - base < CAP) ? blk1 - base : CAP;
        __syncthreads();
        for (int i = threadIdx.x; i < cnt; i += 256)
            lds_csr[i] = csr_src[base + i];
        __syncthreads();
        int lo_e = (gs0 > base ? gs0 : base) - base;
        int hi_e = (gs1 < base + cnt ? gs1 : base + cnt) - base;
        int e = lo_e;
        for (; e + 4 <= hi_e; e += 4) {
            int s0 = lds_csr[e], s1 = lds_csr[e + 1];
            int s2 = lds_csr[e + 2], s3 = lds_csr[e + 3];
            uint4 v0 = gc[(size_t)s0 * 4 + cl];
            uint4 v1 = gc[(size_t)s1 * 4 + cl];
            uint4 v2 = gc[(size_t)s2 * 4 + cl];
            uint4 v3 = gc[(size_t)s3 * 4 + cl];
            uint4 q = pk4(pk4(v0, v1), pk4(v2, v3));   // depth-2 fp16 tree
            float4 flo = up4(make_uint2(q.x, q.y));
            float4 fhi = up4(make_uint2(q.z, q.w));
            accLo.x += flo.x; accLo.y += flo.y; accLo.z += flo.z; accLo.w += flo.w;
            accHi.x += fhi.x; accHi.y += fhi.y; accHi.z += fhi.z; accHi.w += fhi.w;
        }
        for (; e < hi_e; ++e) {
            int s0 = lds_csr[e];
            uint4 v = gc[(size_t)s0 * 4 + cl];
            float4 flo = up4(make_uint2(v.x, v.y));
            float4 fhi = up4(make_uint2(v.z, v.w));
            accLo.x += flo.x; accLo.y += flo.y; accLo.z += flo.z; accLo.w += flo.w;
            accHi.x += fhi.x; accHi.y += fhi.y; accHi.z += fhi.z; accHi.w += fhi.w;
        }
    }
    if (active) {
        float4 bb0 = *(const float4*)&bias[chunk * 32 + cl * 8];
        float4 bb1 = *(const float4*)&bias[chunk * 32 + cl * 8 + 4];
        float4 o0, o1;
        o0.x = fmaf(s, accLo.x, bb0.x);
        o0.y = fmaf(s, accLo.y, bb0.y);
        o0.z = fmaf(s, accLo.z, bb0.z);
        o0.w = fmaf(s, accLo.w, bb0.w);
        o1.x = fmaf(s, accHi.x, bb1.x);
        o1.y = fmaf(s, accHi.y, bb1.y);
        o1.z = fmaf(s, accHi.z, bb1.z);
        o1.w = fmaf(s, accHi.w, bb1.w);
        if (FP16OUT) {
            o0.x = fmaxf(o0.x, 0.f); o0.y = fmaxf(o0.y, 0.f);
            o0.z = fmaxf(o0.z, 0.f); o0.w = fmaxf(o0.w, 0.f);
            o1.x = fmaxf(o1.x, 0.f); o1.y = fmaxf(o1.y, 0.f);
            o1.z = fmaxf(o1.z, 0.f); o1.w = fmaxf(o1.w, 0.f);
            __half2 p0 = __float22half2_rn(make_float2(o0.x, o0.y));
            __half2 p1 = __float22half2_rn(make_float2(o0.z, o0.w));
            __half2 p2 = __float22half2_rn(make_float2(o1.x, o1.y));
            __half2 p3 = __float22half2_rn(make_float2(o1.z, o1.w));
            uint4 pv;
            pv.x = *reinterpret_cast<unsigned*>(&p0);
            pv.y = *reinterpret_cast<unsigned*>(&p1);
            pv.z = *reinterpret_cast<unsigned*>(&p2);
            pv.w = *reinterpret_cast<unsigned*>(&p3);
            ((uint4*)out)[((size_t)chunk * N + node) * 4 + cl] = pv;
        } else {
            ((float4*)out)[(size_t)node * (NCH * 8) + chunk * 8 + cl * 2]     = o0;
            ((float4*)out)[(size_t)node * (NCH * 8) + chunk * 8 + cl * 2 + 1] = o1;
        }
    }
}

extern "C" void kernel_launch(void* const* d_in, const int* in_sizes, int n_in,
                              void* d_out, int out_size, void* d_ws, size_t ws_size,
                              hipStream_t stream) {
    const float* x  = (const float*)d_in[0];
    const float* W1 = (const float*)d_in[1];
    const float* b1 = (const float*)d_in[2];
    const float* W2 = (const float*)d_in[3];
    const float* b2 = (const float*)d_in[4];
    const int* eidx = (const int*)d_in[5];

    const int HID = in_sizes[2];            // 256
    const int OUT = in_sizes[4];            // 64
    const int IN  = in_sizes[1] / HID;      // 512
    const int N   = in_sizes[0] / IN;       // 50000
    const int E   = in_sizes[5] / 2;        // 800000
    const int NB  = (N + 255) >> 8;         // 196 buckets

    char* ws = (char*)d_ws;
    size_t off = 0;
    auto alloc = [&](size_t bytes) {
        off = (off + 255) & ~(size_t)255;
        char* p = ws + off;
        off += bytes;
        return p;
    };
    float* dis       = (float*)alloc((size_t)N * 4);
    int* flag        = (int*)alloc(256);
    int* bcnt        = (int*)alloc(256 * 4);
    int* bbase       = (int*)alloc(260 * 4);
    int* bcur        = (int*)alloc(256 * 4);
    int* offsets     = (int*)alloc((size_t)(N + 1) * 4);
    unsigned* packed = (unsigned*)alloc((size_t)E * 4);
    int* csr_src     = (int*)alloc((size_t)E * 4);
    _Float16* w1t    = (_Float16*)alloc((size_t)IN * HID * 2);
    _Float16* w2t    = (_Float16*)alloc((size_t)HID * OUT * 2);
    _Float16* h1s    = (_Float16*)alloc((size_t)N * HID * 2);   // [8][N][32]
    _Float16* a1s    = (_Float16*)alloc((size_t)N * HID * 2);   // [8][N][32]
    _Float16* h2s    = (_Float16*)alloc((size_t)N * OUT * 2);   // [2][N][32]

    const int nblkE = (E + EPB - 1) / EPB;

    detect_i64_kernel<<<1, 256, 0, stream>>>(eidx, flag, bcnt);
    bin_count_kernel<<<nblkE, 256, 0, stream>>>(eidx, flag, bcnt, E, N);
    scan_buckets_kernel<<<1, 256, 0, stream>>>(bcnt, bbase, bcur, NB);
    bin_scatter_kernel<<<nblkE, 256, 0, stream>>>(eidx, flag, bcur, packed, E, N);
    bucket_sort_kernel<<<NB, 256, 0, stream>>>(packed, bbase, csr_src, offsets, dis, N, NB);
    wt_kernel<<<(IN * HID + HID * OUT + 255) / 256, 256, 0, stream>>>(W1, W2, w1t, w2t);

    // Layer 1
    gemm1_kernel<<<(N + 31) / 32, 256, 0, stream>>>(x, w1t, dis, h1s, N);
    aggv_kernel<8, 1><<<((N + 63) / 64) * 8, 256, 0, stream>>>(h1s, offsets, csr_src, dis,
                                                               b1, a1s, N);
    // Layer 2
    gemm2_kernel<<<(N + 63) / 64, 256, 0, stream>>>(a1s, w2t, dis, h2s, N);
    aggv_kernel<2, 0><<<((N + 63) / 64) * 2, 256, 0, stream>>>(h2s, offsets, csr_src, dis,
                                                               b2, d_out, N);
}

// Round 12
// 149.464 us; speedup vs baseline: 1.1401x; 1.0578x over previous
//
#include <hip/hip_runtime.h>
#include <hip/hip_bf16.h>
#include <hip/hip_fp16.h>
#include <stdint.h>

typedef _Float16 half8_t __attribute__((ext_vector_type(8)));
typedef float f32x4_t __attribute__((ext_vector_type(4)));

// Raw barrier: wait own LDS ops, then s_barrier — WITHOUT the vmcnt(0) drain
// that __syncthreads() emits. Global prefetch loads stay in flight (T4).
#define LBAR() do { asm volatile("s_waitcnt lgkmcnt(0)" ::: "memory"); \
                    __builtin_amdgcn_s_barrier(); } while (0)

// ---------------------------------------------------------------------------
// GCN 2-layer, fp16-MFMA path, chunk-major intermediates:
//   g = (x@W)*dis[row]  stored as [chunk][N][32] fp16 (chunk = 32 cols)
//   out[i] = dis[i]*(sum_e g[src]+g[i]) + b; aggregation chunk-pinned to XCD.
// CSR via dst-bucket binning + per-bucket LDS counting sort.
// gemm1/2: reg-prefetch + raw-barrier loop (prefetch not drained at barriers).
// aggv: 4-lane/uint4 groups, LDS-staged CSR, fp16 pairwise tree.
// ---------------------------------------------------------------------------

__global__ __launch_bounds__(256) void detect_i64_kernel(const int* __restrict__ idx,
                                                         int* __restrict__ flag,
                                                         int* __restrict__ bcnt) {
    int t = threadIdx.x;
    if (t < 64) {
        int v = idx[2 * t + 1];
        unsigned long long b = __ballot(v == 0);
        if (t == 0) *flag = (b == 0xFFFFFFFFFFFFFFFFULL) ? 1 : 0;
    }
    bcnt[t] = 0;
}

__device__ __forceinline__ int load_idx(const int* __restrict__ idx, long long pos, int is64) {
    return is64 ? idx[2 * pos] : idx[pos];
}

#define EPB 4096   // edges per binning block

__global__ __launch_bounds__(256) void bin_count_kernel(
        const int* __restrict__ idx, const int* __restrict__ flag,
        int* __restrict__ bcnt, int E, int N) {
    __shared__ int hist[256];
    hist[threadIdx.x] = 0;
    __syncthreads();
    const int is64 = *flag;
    const int base = blockIdx.x * EPB;
    const int cnt = (E - base < EPB) ? E - base : EPB;
    for (int i = threadIdx.x; i < cnt; i += 256) {
        int d = load_idx(idx, (long long)E + base + i, is64);
        if ((unsigned)d < (unsigned)N) atomicAdd(&hist[d >> 8], 1);
    }
    __syncthreads();
    int h = hist[threadIdx.x];
    if (h) atomicAdd(&bcnt[threadIdx.x], h);
}

__global__ __launch_bounds__(256) void scan_buckets_kernel(
        const int* __restrict__ bcnt, int* __restrict__ bbase,
        int* __restrict__ bcur, int NB) {
    __shared__ int buf[256];
    int t = threadIdx.x;
    int v = (t < NB) ? bcnt[t] : 0;
    buf[t] = v;
    __syncthreads();
    #pragma unroll
    for (int off = 1; off < 256; off <<= 1) {
        int u = (t >= off) ? buf[t - off] : 0;
        __syncthreads();
        buf[t] += u;
        __syncthreads();
    }
    int excl = buf[t] - v;
    if (t < NB) { bbase[t] = excl; bcur[t] = excl; }
    if (t == NB - 1) bbase[NB] = buf[t];
}

__global__ __launch_bounds__(256) void bin_scatter_kernel(
        const int* __restrict__ idx, const int* __restrict__ flag,
        int* __restrict__ bcur, unsigned* __restrict__ packed, int E, int N) {
    __shared__ int cur[256];
    cur[threadIdx.x] = 0;
    __syncthreads();
    const int is64 = *flag;
    const int base = blockIdx.x * EPB;
    const int cnt = (E - base < EPB) ? E - base : EPB;
    for (int i = threadIdx.x; i < cnt; i += 256) {
        int d = load_idx(idx, (long long)E + base + i, is64);
        if ((unsigned)d < (unsigned)N) atomicAdd(&cur[d >> 8], 1);
    }
    __syncthreads();
    int h = cur[threadIdx.x];
    int bs = h ? atomicAdd(&bcur[threadIdx.x], h) : 0;
    __syncthreads();
    cur[threadIdx.x] = bs;
    __syncthreads();
    for (int i = threadIdx.x; i < cnt; i += 256) {
        int d = load_idx(idx, (long long)E + base + i, is64);
        if ((unsigned)d >= (unsigned)N) continue;
        int s = load_idx(idx, base + i, is64);
        if ((unsigned)s >= (unsigned)N) s = 0;
        int pos = atomicAdd(&cur[d >> 8], 1);
        packed[pos] = (unsigned)s | ((unsigned)(d & 255) << 16);
    }
}

__global__ __launch_bounds__(256) void bucket_sort_kernel(
        const unsigned* __restrict__ packed, const int* __restrict__ bbase,
        int* __restrict__ csr_src, int* __restrict__ offsets,
        float* __restrict__ dis, int N, int NB) {
    __shared__ int buf[256];
    __shared__ int cur[256];
    const int b = blockIdx.x;
    const int t = threadIdx.x;
    cur[t] = 0;
    __syncthreads();
    const int e0 = bbase[b], e1 = bbase[b + 1];
    for (int i = e0 + t; i < e1; i += 256)
        atomicAdd(&cur[(packed[i] >> 16) & 255], 1);
    __syncthreads();
    int v = cur[t];
    buf[t] = v;
    __syncthreads();
    #pragma unroll
    for (int off = 1; off < 256; off <<= 1) {
        int u = (t >= off) ? buf[t - off] : 0;
        __syncthreads();
        buf[t] += u;
        __syncthreads();
    }
    int excl = buf[t] - v;
    cur[t] = excl;
    int node = b * 256 + t;
    if (node < N) {
        offsets[node] = e0 + excl;
        dis[node] = rsqrtf((float)(v + 1));   // +1 self-loop
    }
    if (b == NB - 1 && t == 0) offsets[N] = bbase[NB];
    __syncthreads();
    for (int i = e0 + t; i < e1; i += 256) {
        unsigned rec = packed[i];
        int dl = (rec >> 16) & 255;
        int pos = atomicAdd(&cur[dl], 1);
        csr_src[e0 + pos] = (int)(rec & 0xFFFF);
    }
}

// Transpose-convert W1 [512][256] -> w1t fp16 [256][512], W2 [256][64] -> w2t fp16 [64][256].
__global__ void wt_kernel(const float* __restrict__ W1, const float* __restrict__ W2,
                          _Float16* __restrict__ w1t, _Float16* __restrict__ w2t) {
    int p = blockIdx.x * 256 + threadIdx.x;
    if (p < 512 * 256) {
        int k = p >> 8, n = p & 255;
        w1t[n * 512 + k] = (_Float16)W1[p];
    } else {
        int q = p - 512 * 256;
        if (q < 256 * 64) {
            int k = q >> 6, n = q & 63;
            w2t[n * 256 + k] = (_Float16)W2[q];
        }
    }
}

// ---------------------------------------------------------------------------
// GEMM1: h1[chunk][M][32] = fp16( (x[M,512] @ W1) * dis[row] ).
// Tile 64 x 256, BK=32, 4 waves each 64x64 (round-9 geometry), T14 prefetch,
// raw barriers (no vmcnt drain) so the prefetch covers a full iteration.
// ---------------------------------------------------------------------------
__global__ __launch_bounds__(256, 3) void gemm1_kernel(
        const float* __restrict__ x, const _Float16* __restrict__ w1t,
        const float* __restrict__ dis, _Float16* __restrict__ h1s, int M) {
    __shared__ _Float16 As[4 * 65 * 8];    // [kb][row pad65][8]
    __shared__ _Float16 Bs[4 * 257 * 8];   // [kb][col pad257][8]
    const int tid = threadIdx.x;
    const int brow = blockIdx.x * 64;
    const int w = tid >> 6, lane = tid & 63;
    const int wcol = w * 64;
    const int lrow = lane & 15, lkb = lane >> 4;

    const int arow = tid >> 2, akb = tid & 3;
    const int gr = brow + arow;
    const bool aval = gr < M;
    const float* xptr = x + (size_t)(aval ? gr : 0) * 512 + akb * 8;
    const _Float16* bbase = w1t + (size_t)arow * 512 + akb * 8;
    const int awr = (akb * 65 + arow) << 3;
    const int bwr0 = (akb * 257 + arow) << 3;

    f32x4_t acc[4][4];
    #pragma unroll
    for (int mi = 0; mi < 4; ++mi)
        #pragma unroll
        for (int nj = 0; nj < 4; ++nj) acc[mi][nj] = (f32x4_t)0.f;

    float4 au = make_float4(0.f, 0.f, 0.f, 0.f);
    float4 av = make_float4(0.f, 0.f, 0.f, 0.f);
    half8_t bh0, bh1, bh2, bh3;

    // Prefetch tile 0.
    if (aval) { au = *(const float4*)(xptr); av = *(const float4*)(xptr + 4); }
    bh0 = *(const half8_t*)(bbase);
    bh1 = *(const half8_t*)(bbase + 64 * 512);
    bh2 = *(const half8_t*)(bbase + 128 * 512);
    bh3 = *(const half8_t*)(bbase + 192 * 512);

    for (int t = 0; t < 16; ++t) {
        LBAR();                                // all waves done reading prior tile
        half8_t ha;
        ha[0] = (_Float16)au.x; ha[1] = (_Float16)au.y;
        ha[2] = (_Float16)au.z; ha[3] = (_Float16)au.w;
        ha[4] = (_Float16)av.x; ha[5] = (_Float16)av.y;
        ha[6] = (_Float16)av.z; ha[7] = (_Float16)av.w;
        *(half8_t*)&As[awr] = ha;
        *(half8_t*)&Bs[bwr0] = bh0;
        *(half8_t*)&Bs[bwr0 + 64 * 8] = bh1;
        *(half8_t*)&Bs[bwr0 + 128 * 8] = bh2;
        *(half8_t*)&Bs[bwr0 + 192 * 8] = bh3;
        LBAR();                                // tile visible to all waves
        if (t < 15) {                          // prefetch next tile; stays in
            int k0 = (t + 1) * 32;             // flight across the barriers.
            if (aval) {
                au = *(const float4*)(xptr + k0);
                av = *(const float4*)(xptr + k0 + 4);
            }
            bh0 = *(const half8_t*)(bbase + k0);
            bh1 = *(const half8_t*)(bbase + k0 + 64 * 512);
            bh2 = *(const half8_t*)(bbase + k0 + 128 * 512);
            bh3 = *(const half8_t*)(bbase + k0 + 192 * 512);
        }
        half8_t a[4], b[4];
        #pragma unroll
        for (int mi = 0; mi < 4; ++mi)
            a[mi] = *(const half8_t*)&As[(lkb * 65 + mi * 16 + lrow) << 3];
        #pragma unroll
        for (int nj = 0; nj < 4; ++nj)
            b[nj] = *(const half8_t*)&Bs[(lkb * 257 + wcol + nj * 16 + lrow) << 3];
        #pragma unroll
        for (int mi = 0; mi < 4; ++mi)
            #pragma unroll
            for (int nj = 0; nj < 4; ++nj)
                acc[mi][nj] = __builtin_amdgcn_mfma_f32_16x16x32_f16(a[mi], b[nj], acc[mi][nj], 0, 0, 0);
    }
    // Epilogue: C/D layout col=lane&15, row=(lane>>4)*4+r. Chunk-major store.
    #pragma unroll
    for (int mi = 0; mi < 4; ++mi) {
        #pragma unroll
        for (int r = 0; r < 4; ++r) {
            int grow = brow + mi * 16 + (lane >> 4) * 4 + r;
            if (grow >= M) continue;
            float s = dis[grow];
            #pragma unroll
            for (int nj = 0; nj < 4; ++nj) {
                int col = wcol + nj * 16 + lrow;
                h1s[((size_t)(col >> 5) * M + grow) * 32 + (col & 31)] =
                    (_Float16)(acc[mi][nj][r] * s);
            }
        }
    }
}

// ---------------------------------------------------------------------------
// GEMM2: h2[chunk][M][32] = fp16( (a1 @ W2) * dis[row] ), a1 chunk-major.
// Tile 64x64, 4 waves, K=256, T14 reg-prefetch + raw barriers.
// ---------------------------------------------------------------------------
__global__ __launch_bounds__(256, 4) void gemm2_kernel(
        const _Float16* __restrict__ a1s, const _Float16* __restrict__ w2t,
        const float* __restrict__ dis, _Float16* __restrict__ h2s, int M) {
    __shared__ _Float16 As[4 * 65 * 8];
    __shared__ _Float16 Bs[4 * 65 * 8];
    const int tid = threadIdx.x;
    const int brow = blockIdx.x * 64;
    const int w = tid >> 6, lane = tid & 63;
    const int lrow = lane & 15, lkb = lane >> 4;

    const int arow = tid >> 2, akb = tid & 3;
    const int gr = brow + arow;
    const bool aval = gr < M;
    const _Float16* aptr = a1s + ((size_t)(aval ? gr : 0)) * 32 + akb * 8;
    const _Float16* bptr = w2t + (size_t)arow * 256 + akb * 8;
    const int awr = (akb * 65 + arow) << 3;

    f32x4_t acc[4];
    #pragma unroll
    for (int nj = 0; nj < 4; ++nj) acc[nj] = (f32x4_t)0.f;

    const half8_t zero8 = (half8_t)(_Float16)0.f;
    half8_t ah = zero8, bh;
    if (aval) ah = *(const half8_t*)(aptr);
    bh = *(const half8_t*)(bptr);

    for (int t = 0; t < 8; ++t) {
        LBAR();
        *(half8_t*)&As[awr] = ah;
        *(half8_t*)&Bs[awr] = bh;
        LBAR();
        if (t < 7) {
            if (aval) ah = *(const half8_t*)(aptr + (size_t)(t + 1) * M * 32);
            bh = *(const half8_t*)(bptr + (t + 1) * 32);
        }
        half8_t a = *(const half8_t*)&As[(lkb * 65 + w * 16 + lrow) << 3];
        half8_t b[4];
        #pragma unroll
        for (int nj = 0; nj < 4; ++nj)
            b[nj] = *(const half8_t*)&Bs[(lkb * 65 + nj * 16 + lrow) << 3];
        #pragma unroll
        for (int nj = 0; nj < 4; ++nj)
            acc[nj] = __builtin_amdgcn_mfma_f32_16x16x32_f16(a, b[nj], acc[nj], 0, 0, 0);
    }
    #pragma unroll
    for (int r = 0; r < 4; ++r) {
        int grow = brow + w * 16 + (lane >> 4) * 4 + r;
        if (grow >= M) continue;
        float s = dis[grow];
        #pragma unroll
        for (int nj = 0; nj < 4; ++nj) {
            int col = nj * 16 + lrow;
            h2s[((size_t)(col >> 5) * M + grow) * 32 + (col & 31)] =
                (_Float16)(acc[nj][r] * s);
        }
    }
}

__device__ __forceinline__ float4 up4(uint2 v) {
    __half2 h0 = *reinterpret_cast<__half2*>(&v.x);
    __half2 h1 = *reinterpret_cast<__half2*>(&v.y);
    float2 a = __half22float2(h0), b = __half22float2(h1);
    return make_float4(a.x, a.y, b.x, b.y);
}

__device__ __forceinline__ unsigned pkw(unsigned a, unsigned b) {
    __half2 ha = *reinterpret_cast<__half2*>(&a);
    __half2 hb = *reinterpret_cast<__half2*>(&b);
    __half2 r = __hadd2(ha, hb);
    return *reinterpret_cast<unsigned*>(&r);
}

__device__ __forceinline__ uint4 pk4(uint4 a, uint4 b) {
    uint4 r;
    r.x = pkw(a.x, b.x);
    r.y = pkw(a.y, b.y);
    r.z = pkw(a.z, b.z);
    r.w = pkw(a.w, b.w);
    return r;
}

// ---------------------------------------------------------------------------
// Chunked aggregation over [NCH][N][32] fp16, chunk pinned via blockIdx % NCH.
// Block = 64 nodes; stages the block's contiguous CSR slice into LDS.
// 4-lane group per node (lane = uint4 = 8 fp16); depth-2 fp16 pairwise tree,
// f32 master accumulators.
// ---------------------------------------------------------------------------
template<int NCH, int FP16OUT>
__global__ __launch_bounds__(256) void aggv_kernel(
        const _Float16* __restrict__ g, const int* __restrict__ offsets,
        const int* __restrict__ csr_src, const float* __restrict__ dis,
        const float* __restrict__ bias, void* __restrict__ out, int N) {
    constexpr int CAP = 2048;
    __shared__ int lds_csr[CAP];
    const int chunk = blockIdx.x % NCH;
    const int nodeBase = (blockIdx.x / NCH) * 64;
    const int grp = threadIdx.x >> 2;     // 0..63
    const int cl = threadIdx.x & 3;       // uint4 slot (8 fp16)
    const int node = nodeBase + grp;
    const bool active = node < N;
    const int nend = (nodeBase + 64 < N) ? nodeBase + 64 : N;
    const int blk0 = offsets[nodeBase];
    const int blk1 = offsets[nend];
    const uint4* gc = (const uint4*)g + (size_t)chunk * N * 4;   // row = 4 uint4

    int gs0 = 0, gs1 = 0;
    float s = 0.f;
    if (active) { gs0 = offsets[node]; gs1 = offsets[node + 1]; s = dis[node]; }

    float4 accLo = make_float4(0.f, 0.f, 0.f, 0.f);
    float4 accHi = make_float4(0.f, 0.f, 0.f, 0.f);
    if (active) {
        uint4 sv = gc[(size_t)node * 4 + cl];                    // self-loop
        float4 lo = up4(make_uint2(sv.x, sv.y));
        float4 hi = up4(make_uint2(sv.z, sv.w));
        accLo.x += lo.x; accLo.y += lo.y; accLo.z += lo.z; accLo.w += lo.w;
        accHi.x += hi.x; accHi.y += hi.y; accHi.z += hi.z; accHi.w += hi.w;
    }

    for (int base = blk0; base < blk1; base += CAP) {
        const int cnt = (blk1 - base < CAP) ? blk1 - base : CAP;
        __syncthreads();
        for (int i = threadIdx.x; i < cnt; i += 256)
            lds_csr[i] = csr_src[base + i];
        __syncthreads();
        int lo_e = (gs0 > base ? gs0 : base) - base;
        int hi_e = (gs1 < base + cnt ? gs1 : base + cnt) - base;
        int e = lo_e;
        for (; e + 4 <= hi_e; e += 4) {
            int s0 = lds_csr[e], s1 = lds_csr[e + 1];
            int s2 = lds_csr[e + 2], s3 = lds_csr[e + 3];
            uint4 v0 = gc[(size_t)s0 * 4 + cl];
            uint4 v1 = gc[(size_t)s1 * 4 + cl];
            uint4 v2 = gc[(size_t)s2 * 4 + cl];
            uint4 v3 = gc[(size_t)s3 * 4 + cl];
            uint4 q = pk4(pk4(v0, v1), pk4(v2, v3));   // depth-2 fp16 tree
            float4 flo = up4(make_uint2(q.x, q.y));
            float4 fhi = up4(make_uint2(q.z, q.w));
            accLo.x += flo.x; accLo.y += flo.y; accLo.z += flo.z; accLo.w += flo.w;
            accHi.x += fhi.x; accHi.y += fhi.y; accHi.z += fhi.z; accHi.w += fhi.w;
        }
        for (; e < hi_e; ++e) {
            int s0 = lds_csr[e];
            uint4 v = gc[(size_t)s0 * 4 + cl];
            float4 flo = up4(make_uint2(v.x, v.y));
            float4 fhi = up4(make_uint2(v.z, v.w));
            accLo.x += flo.x; accLo.y += flo.y; accLo.z += flo.z; accLo.w += flo.w;
            accHi.x += fhi.x; accHi.y += fhi.y; accHi.z += fhi.z; accHi.w += fhi.w;
        }
    }
    if (active) {
        float4 bb0 = *(const float4*)&bias[chunk * 32 + cl * 8];
        float4 bb1 = *(const float4*)&bias[chunk * 32 + cl * 8 + 4];
        float4 o0, o1;
        o0.x = fmaf(s, accLo.x, bb0.x);
        o0.y = fmaf(s, accLo.y, bb0.y);
        o0.z = fmaf(s, accLo.z, bb0.z);
        o0.w = fmaf(s, accLo.w, bb0.w);
        o1.x = fmaf(s, accHi.x, bb1.x);
        o1.y = fmaf(s, accHi.y, bb1.y);
        o1.z = fmaf(s, accHi.z, bb1.z);
        o1.w = fmaf(s, accHi.w, bb1.w);
        if (FP16OUT) {
            o0.x = fmaxf(o0.x, 0.f); o0.y = fmaxf(o0.y, 0.f);
            o0.z = fmaxf(o0.z, 0.f); o0.w = fmaxf(o0.w, 0.f);
            o1.x = fmaxf(o1.x, 0.f); o1.y = fmaxf(o1.y, 0.f);
            o1.z = fmaxf(o1.z, 0.f); o1.w = fmaxf(o1.w, 0.f);
            __half2 p0 = __float22half2_rn(make_float2(o0.x, o0.y));
            __half2 p1 = __float22half2_rn(make_float2(o0.z, o0.w));
            __half2 p2 = __float22half2_rn(make_float2(o1.x, o1.y));
            __half2 p3 = __float22half2_rn(make_float2(o1.z, o1.w));
            uint4 pv;
            pv.x = *reinterpret_cast<unsigned*>(&p0);
            pv.y = *reinterpret_cast<unsigned*>(&p1);
            pv.z = *reinterpret_cast<unsigned*>(&p2);
            pv.w = *reinterpret_cast<unsigned*>(&p3);
            ((uint4*)out)[((size_t)chunk * N + node) * 4 + cl] = pv;
        } else {
            ((float4*)out)[(size_t)node * (NCH * 8) + chunk * 8 + cl * 2]     = o0;
            ((float4*)out)[(size_t)node * (NCH * 8) + chunk * 8 + cl * 2 + 1] = o1;
        }
    }
}

extern "C" void kernel_launch(void* const* d_in, const int* in_sizes, int n_in,
                              void* d_out, int out_size, void* d_ws, size_t ws_size,
                              hipStream_t stream) {
    const float* x  = (const float*)d_in[0];
    const float* W1 = (const float*)d_in[1];
    const float* b1 = (const float*)d_in[2];
    const float* W2 = (const float*)d_in[3];
    const float* b2 = (const float*)d_in[4];
    const int* eidx = (const int*)d_in[5];

    const int HID = in_sizes[2];            // 256
    const int OUT = in_sizes[4];            // 64
    const int IN  = in_sizes[1] / HID;      // 512
    const int N   = in_sizes[0] / IN;       // 50000
    const int E   = in_sizes[5] / 2;        // 800000
    const int NB  = (N + 255) >> 8;         // 196 buckets

    char* ws = (char*)d_ws;
    size_t off = 0;
    auto alloc = [&](size_t bytes) {
        off = (off + 255) & ~(size_t)255;
        char* p = ws + off;
        off += bytes;
        return p;
    };
    float* dis       = (float*)alloc((size_t)N * 4);
    int* flag        = (int*)alloc(256);
    int* bcnt        = (int*)alloc(256 * 4);
    int* bbase       = (int*)alloc(260 * 4);
    int* bcur        = (int*)alloc(256 * 4);
    int* offsets     = (int*)alloc((size_t)(N + 1) * 4);
    unsigned* packed = (unsigned*)alloc((size_t)E * 4);
    int* csr_src     = (int*)alloc((size_t)E * 4);
    _Float16* w1t    = (_Float16*)alloc((size_t)IN * HID * 2);
    _Float16* w2t    = (_Float16*)alloc((size_t)HID * OUT * 2);
    _Float16* h1s    = (_Float16*)alloc((size_t)N * HID * 2);   // [8][N][32]
    _Float16* a1s    = (_Float16*)alloc((size_t)N * HID * 2);   // [8][N][32]
    _Float16* h2s    = (_Float16*)alloc((size_t)N * OUT * 2);   // [2][N][32]

    const int nblkE = (E + EPB - 1) / EPB;

    detect_i64_kernel<<<1, 256, 0, stream>>>(eidx, flag, bcnt);
    bin_count_kernel<<<nblkE, 256, 0, stream>>>(eidx, flag, bcnt, E, N);
    scan_buckets_kernel<<<1, 256, 0, stream>>>(bcnt, bbase, bcur, NB);
    bin_scatter_kernel<<<nblkE, 256, 0, stream>>>(eidx, flag, bcur, packed, E, N);
    bucket_sort_kernel<<<NB, 256, 0, stream>>>(packed, bbase, csr_src, offsets, dis, N, NB);
    wt_kernel<<<(IN * HID + HID * OUT + 255) / 256, 256, 0, stream>>>(W1, W2, w1t, w2t);

    // Layer 1
    gemm1_kernel<<<(N + 63) / 64, 256, 0, stream>>>(x, w1t, dis, h1s, N);
    aggv_kernel<8, 1><<<((N + 63) / 64) * 8, 256, 0, stream>>>(h1s, offsets, csr_src, dis,
                                                               b1, a1s, N);
    // Layer 2
    gemm2_kernel<<<(N + 63) / 64, 256, 0, stream>>>(a1s, w2t, dis, h2s, N);
    aggv_kernel<2, 0><<<((N + 63) / 64) * 2, 256, 0, stream>>>(h2s, offsets, csr_src, dis,
                                                               b2, d_out, N);
}